// Round 2
// baseline (123.774 us; speedup 1.0000x reference)
//
#include <hip/hip_runtime.h>

// Problem constants (match reference)
#define N_WORDS   16384
#define MAX_WLEN  16
#define HIDDEN    300
#define N_LETTERS 128
#define KSIZE     3

#define TROW 300          // floats per table row (one letter, one tap)
#define TLET 129          // 128 letters + 1 zero row for padding
#define CH4  75           // 300 / 4 float4 chunks per row

#define T_FLOATS   (3 * TLET * TROW)            // 116,100 floats
#define T_BYTES    (T_FLOATS * 4)               // 464,400 B
#define WT_FLOATS  (HIDDEN * HIDDEN * KSIZE)    // 270,000 floats
#define WT_BYTES   (WT_FLOATS * 4)              // 1,080,000 B

// ---------------------------------------------------------------------------
// Kernel 0: LDS-tiled transpose  w[300 o][900 ik]  ->  w_t[900 ik][300 o]
// so the precompute kernel reads w coalesced (lanes = consecutive o).
// ---------------------------------------------------------------------------
__global__ __launch_bounds__(256) void transpose_w(
    const float* __restrict__ in,    // [300][900]
    float* __restrict__ out)         // [900][300]
{
    __shared__ float tile[64][65];
    const int bx = blockIdx.x * 64;          // ik-dim (cols of in)
    const int by = blockIdx.y * 64;          // o-dim  (rows of in)
    const int tx = threadIdx.x & 63;
    const int ty = threadIdx.x >> 6;         // 0..3

    #pragma unroll
    for (int r = ty; r < 64; r += 4) {
        const int row = by + r, col = bx + tx;
        tile[r][tx] = (row < HIDDEN && col < HIDDEN * KSIZE)
                          ? in[row * (HIDDEN * KSIZE) + col] : 0.0f;
    }
    __syncthreads();
    #pragma unroll
    for (int r = ty; r < 64; r += 4) {
        const int row = bx + r, col = by + tx;   // out is [900][300]
        if (row < HIDDEN * KSIZE && col < HIDDEN)
            out[row * HIDDEN + col] = tile[tx][r];
    }
}

// ---------------------------------------------------------------------------
// Kernel 1 (coalesced variant): E_k[c, o] = sum_i emb[c,i] * w[o,i,k]
// reads w_t[900][300]: per i, three contiguous 1200 B rows (lanes = o).
// T layout: T[k][TLET][TROW], letter 128 == all zeros (conv zero padding).
// ---------------------------------------------------------------------------
__global__ __launch_bounds__(320) void precompute_table_T(
    const float* __restrict__ emb,   // [128][300]
    const float* __restrict__ wt,    // [900][300]  (ik-major)
    float* __restrict__ T)           // [3][129][300]
{
    __shared__ float emb_s[HIDDEN];
    const int c = blockIdx.x;        // 0..128
    const int o = threadIdx.x;       // 0..319 (300 active)

    if (c == N_LETTERS) {
        if (o < HIDDEN) {
            T[0 * TLET * TROW + c * TROW + o] = 0.0f;
            T[1 * TLET * TROW + c * TROW + o] = 0.0f;
            T[2 * TLET * TROW + c * TROW + o] = 0.0f;
        }
        return;
    }

    if (o < HIDDEN) emb_s[o] = emb[c * HIDDEN + o];
    __syncthreads();
    if (o >= HIDDEN) return;

    float s0 = 0.0f, s1 = 0.0f, s2 = 0.0f;
    #pragma unroll 10
    for (int i = 0; i < HIDDEN; ++i) {
        const float e = emb_s[i];
        const float* __restrict__ row = wt + i * (3 * HIDDEN);
        s0 = fmaf(e, row[o], s0);
        s1 = fmaf(e, row[HIDDEN + o], s1);
        s2 = fmaf(e, row[2 * HIDDEN + o], s2);
    }
    T[0 * TLET * TROW + c * TROW + o] = s0;
    T[1 * TLET * TROW + c * TROW + o] = s1;
    T[2 * TLET * TROW + c * TROW + o] = s2;
}

// Fallback variant (reads original w layout) if ws_size can't fit w_t.
__global__ __launch_bounds__(320) void precompute_table(
    const float* __restrict__ emb,   // [128][300]
    const float* __restrict__ w,     // [300][300][3]  (O, I, K)
    float* __restrict__ T)           // [3][129][300]
{
    __shared__ float emb_s[HIDDEN];
    const int c = blockIdx.x;
    const int o = threadIdx.x;

    if (c == N_LETTERS) {
        if (o < HIDDEN) {
            T[0 * TLET * TROW + c * TROW + o] = 0.0f;
            T[1 * TLET * TROW + c * TROW + o] = 0.0f;
            T[2 * TLET * TROW + c * TROW + o] = 0.0f;
        }
        return;
    }
    if (o < HIDDEN) emb_s[o] = emb[c * HIDDEN + o];
    __syncthreads();
    if (o >= HIDDEN) return;

    float s0 = 0.0f, s1 = 0.0f, s2 = 0.0f;
    const float* __restrict__ wp = w + (size_t)o * HIDDEN * KSIZE;
    #pragma unroll 4
    for (int i = 0; i < HIDDEN; ++i) {
        const float e = emb_s[i];
        s0 = fmaf(e, wp[i * 3 + 0], s0);
        s1 = fmaf(e, wp[i * 3 + 1], s1);
        s2 = fmaf(e, wp[i * 3 + 2], s2);
    }
    T[0 * TLET * TROW + c * TROW + o] = s0;
    T[1 * TLET * TROW + c * TROW + o] = s1;
    T[2 * TLET * TROW + c * TROW + o] = s2;
}

// ---------------------------------------------------------------------------
// Kernel 2: per word n, per channel-chunk ch (4 channels):
//   s_l = E0[c_{l-1}] + E1[c_l] + E2[c_{l+1}]   (pad letters -> zero row 128)
//   out[n, :] = relu(max_l s_l + bias)
// Thread g -> (n = g/75, ch = g%75). 16384*75 threads, exact grid.
// ---------------------------------------------------------------------------
__global__ __launch_bounds__(256) void conv_gather(
    const int*   __restrict__ words,  // [16][16384]
    const float* __restrict__ T,      // [3][129][300]
    const float* __restrict__ bias,   // [300]
    float*       __restrict__ out)    // [16384][300]
{
    const unsigned g  = blockIdx.x * 256u + threadIdx.x;   // < 16384*75
    const unsigned n  = g / CH4;
    const unsigned ch = g % CH4;

    // letters with zero-pad sentinels at both ends
    int c[MAX_WLEN + 2];
    c[0] = N_LETTERS;
    c[MAX_WLEN + 1] = N_LETTERS;
    #pragma unroll
    for (int l = 0; l < MAX_WLEN; ++l)
        c[l + 1] = words[l * N_WORDS + n];

    const float4* __restrict__ T0 = (const float4*)T;          // [129][75]
    const float4* __restrict__ T1 = T0 + TLET * CH4;
    const float4* __restrict__ T2 = T1 + TLET * CH4;

    float4 m = make_float4(-1e30f, -1e30f, -1e30f, -1e30f);
    #pragma unroll
    for (int l = 0; l < MAX_WLEN; ++l) {
        const float4 a = T0[c[l]     * CH4 + ch];   // tap k=0 reads c_{l-1}
        const float4 b = T1[c[l + 1] * CH4 + ch];   // tap k=1 reads c_l
        const float4 d = T2[c[l + 2] * CH4 + ch];   // tap k=2 reads c_{l+1}
        m.x = fmaxf(m.x, a.x + b.x + d.x);
        m.y = fmaxf(m.y, a.y + b.y + d.y);
        m.z = fmaxf(m.z, a.z + b.z + d.z);
        m.w = fmaxf(m.w, a.w + b.w + d.w);
    }

    const float4 bb = ((const float4*)bias)[ch];
    float4 r;
    r.x = fmaxf(m.x + bb.x, 0.0f);
    r.y = fmaxf(m.y + bb.y, 0.0f);
    r.z = fmaxf(m.z + bb.z, 0.0f);
    r.w = fmaxf(m.w + bb.w, 0.0f);
    ((float4*)out)[g] = r;
}

// ---------------------------------------------------------------------------
extern "C" void kernel_launch(void* const* d_in, const int* in_sizes, int n_in,
                              void* d_out, int out_size, void* d_ws, size_t ws_size,
                              hipStream_t stream) {
    const int*   words = (const int*)  d_in[0];   // [16][16384] int32
    const float* emb   = (const float*)d_in[1];   // [128][300]
    const float* w     = (const float*)d_in[2];   // [300][300][3]
    const float* bias  = (const float*)d_in[3];   // [300]
    float*       out   = (float*)d_out;           // [16384][300]

    float* T  = (float*)d_ws;                     // 464.4 KB
    float* wt = (float*)((char*)d_ws + T_BYTES);  // 1.08 MB (if it fits)

    // ws_size is a host constant across calls -> branch is graph-capture safe.
    if (ws_size >= (size_t)(T_BYTES + WT_BYTES)) {
        dim3 tgrid((HIDDEN * KSIZE + 63) / 64, (HIDDEN + 63) / 64);  // 15 x 5
        transpose_w<<<tgrid, 256, 0, stream>>>(w, wt);
        precompute_table_T<<<TLET, 320, 0, stream>>>(emb, wt, T);
    } else {
        precompute_table<<<TLET, 320, 0, stream>>>(emb, w, T);
    }

    const int total  = N_WORDS * CH4;             // 1,228,800
    const int blocks = total / 256;               // 4800 exactly
    conv_gather<<<blocks, 256, 0, stream>>>(words, T, bias, out);
}

// Round 3
// 112.592 us; speedup vs baseline: 1.0993x; 1.0993x over previous
//
#include <hip/hip_runtime.h>
#include <hip/hip_fp16.h>

// Problem constants (match reference)
#define N_WORDS   16384
#define MAX_WLEN  16
#define HIDDEN    300
#define N_LETTERS 128
#define KSIZE     3

#define TLET   129            // 128 letters + 1 zero row (conv zero-padding)
#define TPAD   304            // table row padded to 304 halfs (38 chunks of 8)
#define CH8    38             // 8-channel chunks per row (304/8); last is half-valid
#define THREADS_TOTAL (N_WORDS * CH8)

#define WT_FLOATS  (HIDDEN * HIDDEN * KSIZE)       // 270,000 floats
#define WT_BYTES   (WT_FLOATS * 4)                 // 1,080,000 B (16B-aligned)
#define T16_HALFS  (3 * TLET * TPAD)               // 117,648 halfs
#define T16_BYTES  (T16_HALFS * 2)                 // 235,296 B

// ---------------------------------------------------------------------------
// Kernel 0: LDS-tiled transpose  w[300 o][900 ik] -> wt[900 ik][300 o]
// so the precompute kernel reads w coalesced (lanes = consecutive o).
// ---------------------------------------------------------------------------
__global__ __launch_bounds__(256) void transpose_w(
    const float* __restrict__ in,    // [300][900]
    float* __restrict__ out)         // [900][300]
{
    __shared__ float tile[64][65];
    const int bx = blockIdx.x * 64;          // ik-dim (cols of in)
    const int by = blockIdx.y * 64;          // o-dim  (rows of in)
    const int tx = threadIdx.x & 63;
    const int ty = threadIdx.x >> 6;         // 0..3

    #pragma unroll
    for (int r = ty; r < 64; r += 4) {
        const int row = by + r, col = bx + tx;
        tile[r][tx] = (row < HIDDEN && col < HIDDEN * KSIZE)
                          ? in[row * (HIDDEN * KSIZE) + col] : 0.0f;
    }
    __syncthreads();
    #pragma unroll
    for (int r = ty; r < 64; r += 4) {
        const int row = bx + r, col = by + tx;   // out is [900][300]
        if (row < HIDDEN * KSIZE && col < HIDDEN)
            out[row * HIDDEN + col] = tile[tx][r];
    }
}

// ---------------------------------------------------------------------------
// Kernel 1 v2: E_k[c,o] = sum_i emb[c,i] * wt[3i+k][o], written as fp16 into
// T16[k][c][o] with rows padded to 304 (pad halfs zeroed).
// Grid (129, 3) = 387 blocks, 320 threads (300 compute, 4 pad-writers).
// ---------------------------------------------------------------------------
__global__ __launch_bounds__(320) void precompute_fp16(
    const float* __restrict__ emb,   // [128][300]
    const float* __restrict__ wt,    // [900][300] (ik-major)
    __half* __restrict__ T16)        // [3][129][304]
{
    __shared__ float emb_s[HIDDEN];
    const int c = blockIdx.x;        // 0..128
    const int k = blockIdx.y;        // 0..2
    const int o = threadIdx.x;       // 0..319
    __half* __restrict__ row_out = T16 + ((size_t)k * TLET + c) * TPAD;

    if (c == N_LETTERS) {            // zero-padding letter row
        if (o < TPAD) row_out[o] = __float2half(0.0f);
        return;
    }

    if (o < HIDDEN) emb_s[o] = emb[c * HIDDEN + o];
    __syncthreads();

    if (o >= HIDDEN) {               // zero the 4 pad channels
        if (o < TPAD) row_out[o] = __float2half(0.0f);
        return;
    }

    float s = 0.0f;
    const float* __restrict__ base = wt + k * HIDDEN + o;   // row (0*3+k), col o
    #pragma unroll 12
    for (int i = 0; i < HIDDEN; ++i)
        s = fmaf(emb_s[i], base[i * (3 * HIDDEN)], s);
    row_out[o] = __float2half(s);
}

// ---------------------------------------------------------------------------
// Kernel 2: thread g -> (word n = g/38, chunk ch8 = g%38, 8 channels).
//   s_l = E0[c_{l-1}] + E1[c_l] + E2[c_{l+1}]   (pad letters -> zero row 128)
//   out[n, ch8*8 .. +7] = relu(max_l s_l + bias)       (tail chunk: 4 valid)
// Table reads: one 16 B (8 x fp16) load per tap per l, L2-resident.
// ---------------------------------------------------------------------------
union H8 { uint4 u; __half2 h2[4]; };

__global__ __launch_bounds__(256) void conv_gather_f16(
    const int*    __restrict__ words,  // [16][16384]
    const __half* __restrict__ T16,    // [3][129][304]
    const float*  __restrict__ bias,   // [300]
    float*        __restrict__ out)    // [16384][300]
{
    const unsigned g   = blockIdx.x * 256u + threadIdx.x;   // < 16384*38
    const unsigned n   = g / CH8;
    const unsigned ch8 = g % CH8;

    // letters with zero-pad sentinels at both ends
    int c[MAX_WLEN + 2];
    c[0] = N_LETTERS;
    c[MAX_WLEN + 1] = N_LETTERS;
    #pragma unroll
    for (int l = 0; l < MAX_WLEN; ++l)
        c[l + 1] = words[l * N_WORDS + n];

    const __half* __restrict__ T0 = T16;
    const __half* __restrict__ T1 = T16 + (size_t)TLET * TPAD;
    const __half* __restrict__ T2 = T16 + (size_t)2 * TLET * TPAD;
    const unsigned cho = ch8 * 8;

    float m[8];
    #pragma unroll
    for (int j = 0; j < 8; ++j) m[j] = -1e30f;

    #pragma unroll
    for (int l = 0; l < MAX_WLEN; ++l) {
        H8 a, b, d;
        a.u = *(const uint4*)(T0 + (unsigned)c[l]     * TPAD + cho);  // tap 0: c_{l-1}
        b.u = *(const uint4*)(T1 + (unsigned)c[l + 1] * TPAD + cho);  // tap 1: c_l
        d.u = *(const uint4*)(T2 + (unsigned)c[l + 2] * TPAD + cho);  // tap 2: c_{l+1}
        #pragma unroll
        for (int j = 0; j < 4; ++j) {
            const float2 fa = __half22float2(a.h2[j]);
            const float2 fb = __half22float2(b.h2[j]);
            const float2 fd = __half22float2(d.h2[j]);
            m[2 * j]     = fmaxf(m[2 * j],     fa.x + fb.x + fd.x);
            m[2 * j + 1] = fmaxf(m[2 * j + 1], fa.y + fb.y + fd.y);
        }
    }

    // bias + relu + store (tail chunk ch8==37 has only 4 valid channels)
    const float4* __restrict__ bias4 = (const float4*)bias;
    float4* __restrict__ out4 = (float4*)(out + (size_t)n * HIDDEN) + ch8 * 2;
    const bool tail = (ch8 == CH8 - 1);

    const float4 b0 = bias4[ch8 * 2];
    float4 r0;
    r0.x = fmaxf(m[0] + b0.x, 0.0f);
    r0.y = fmaxf(m[1] + b0.y, 0.0f);
    r0.z = fmaxf(m[2] + b0.z, 0.0f);
    r0.w = fmaxf(m[3] + b0.w, 0.0f);
    out4[0] = r0;

    if (!tail) {
        const float4 b1 = bias4[ch8 * 2 + 1];
        float4 r1;
        r1.x = fmaxf(m[4] + b1.x, 0.0f);
        r1.y = fmaxf(m[5] + b1.y, 0.0f);
        r1.z = fmaxf(m[6] + b1.z, 0.0f);
        r1.w = fmaxf(m[7] + b1.w, 0.0f);
        out4[1] = r1;
    }
}

// ---------------------------------------------------------------------------
extern "C" void kernel_launch(void* const* d_in, const int* in_sizes, int n_in,
                              void* d_out, int out_size, void* d_ws, size_t ws_size,
                              hipStream_t stream) {
    const int*   words = (const int*)  d_in[0];   // [16][16384] int32
    const float* emb   = (const float*)d_in[1];   // [128][300]
    const float* w     = (const float*)d_in[2];   // [300][300][3]
    const float* bias  = (const float*)d_in[3];   // [300]
    float*       out   = (float*)d_out;           // [16384][300]

    float*  wt  = (float*)d_ws;                        // 1.08 MB
    __half* T16 = (__half*)((char*)d_ws + WT_BYTES);   // 235 KB

    dim3 tgrid((HIDDEN * KSIZE + 63) / 64, (HIDDEN + 63) / 64);  // 15 x 5
    transpose_w<<<tgrid, 256, 0, stream>>>(w, wt);

    dim3 pgrid(TLET, KSIZE);                                     // 129 x 3
    precompute_fp16<<<pgrid, 320, 0, stream>>>(emb, wt, T16);

    const int blocks = THREADS_TOTAL / 256;                      // 2432 exactly
    conv_gather_f16<<<blocks, 256, 0, stream>>>(words, T16, bias, out);
}

// Round 10
// 107.950 us; speedup vs baseline: 1.1466x; 1.0430x over previous
//
#include <hip/hip_runtime.h>
#include <hip/hip_fp16.h>

// Problem constants (match reference)
#define N_WORDS   16384
#define MAX_WLEN  16
#define HIDDEN    300
#define N_LETTERS 128
#define KSIZE     3

#define RPAD   304            // padded row length (elems) for wtb (bf16) and T16 (fp16)
#define CH8    38             // 8-channel fp16 chunks per table row (304/8)
#define TROWS  N_LETTERS      // 128 letter rows per tap

#define WTB_ELEMS (HIDDEN * KSIZE * RPAD)   // 900*304 bf16
#define WTB_BYTES (WTB_ELEMS * 2)           // 547,200 B (16B-aligned)

// gather-LDS geometry
#define NCH_SL   10           // chunks per slice window (windows at 0,10,20,28)
#define W_BLK    64           // words per gather block
#define GTHREADS 640          // 10 waves; exactly 1 item per thread

__device__ __forceinline__ float bf16_to_f32(unsigned short h) {
    union { unsigned int u; float f; } v; v.u = ((unsigned int)h) << 16; return v.f;
}
__device__ __forceinline__ unsigned short f32_to_bf16(float f) {
    union { float f; unsigned int u; } v; v.f = f;
    const unsigned int r = v.u + 0x7fffu + ((v.u >> 16) & 1u);   // RTN-even
    return (unsigned short)(r >> 16);
}

// ---------------------------------------------------------------------------
// Kernel 0: LDS-tiled transpose+downcast
//   w[300 o][900 ik] (f32)  ->  wtb[k][300 i][304 o] (bf16, k-major)
// ---------------------------------------------------------------------------
__global__ __launch_bounds__(256) void transpose_w_bf16(
    const float* __restrict__ in,          // [300][900] f32
    unsigned short* __restrict__ out)      // [3][300][304] bf16
{
    __shared__ float tile[64][65];
    const int bx = blockIdx.x * 64;        // ik-dim (cols of in)
    const int by = blockIdx.y * 64;        // o-dim  (rows of in)
    const int tx = threadIdx.x & 63;
    const int ty = threadIdx.x >> 6;       // 0..3

    #pragma unroll
    for (int r = ty; r < 64; r += 4) {
        const int row = by + r, col = bx + tx;
        tile[r][tx] = (row < HIDDEN && col < HIDDEN * KSIZE)
                          ? in[row * (HIDDEN * KSIZE) + col] : 0.0f;
    }
    __syncthreads();
    #pragma unroll
    for (int r = ty; r < 64; r += 4) {
        const int ik = bx + r, o = by + tx;
        if (ik < HIDDEN * KSIZE && o < HIDDEN) {
            const int i = ik / 3, k = ik % 3;              // in col = i*3+k
            out[((size_t)k * HIDDEN + i) * RPAD + o] = f32_to_bf16(tile[tx][r]);
        }
    }
}

// ---------------------------------------------------------------------------
// Kernel 1: E_k[c,o] = sum_i emb[c,i] * w[o,i,k]  (w read as bf16, fp32 accum),
// written fp16 into T16[k][c][o], rows padded to 304 (pads zeroed).
// Grid (128, 3), 320 threads (300 compute + pad-writers).
// ---------------------------------------------------------------------------
__global__ __launch_bounds__(320) void precompute_f16(
    const float* __restrict__ emb,            // [128][300] f32
    const unsigned short* __restrict__ wtb,   // [3][300][304] bf16
    __half* __restrict__ T16)                 // [3][128][304] fp16
{
    __shared__ float emb_s[HIDDEN];
    const int c = blockIdx.x;        // 0..127
    const int k = blockIdx.y;        // 0..2
    const int o = threadIdx.x;       // 0..319
    __half* __restrict__ row_out = T16 + ((size_t)k * TROWS + c) * RPAD;

    if (o < HIDDEN) emb_s[o] = emb[c * HIDDEN + o];
    __syncthreads();

    if (o >= HIDDEN) {               // zero the 4 pad channels (tail chunk reads them)
        if (o < RPAD) row_out[o] = __float2half(0.0f);
        return;
    }

    float s = 0.0f;
    const unsigned short* __restrict__ base = wtb + (size_t)k * HIDDEN * RPAD + o;
    #pragma unroll 10
    for (int i = 0; i < HIDDEN; ++i)
        s = fmaf(emb_s[i], bf16_to_f32(base[i * RPAD]), s);
    row_out[o] = __float2half(s);
}

// ---------------------------------------------------------------------------
// Kernel 2: LDS-staged gather.
// Grid (256 word-groups, 4 slice-windows). Block: 640 threads, 1 item each.
//  - stage T16 slice [3][128][chunks off..off+9] into LDS (61,440 B)
//  - item = (word wloc 0..63, slice-chunk ch 0..9):
//      s_l = E0[c_{l-1}] + E1[c_l] + E2[c_{l+1}]  (boundary taps are the conv
//      zero-pad reads and are dropped: l=0 and l=15 use 2 taps)
//      out[n, ch8*8 .. +7] = relu(max_l s_l + bias)
// Windows {0,10,20,28}: chunks 28,29 computed twice -> identical stores, benign.
// ---------------------------------------------------------------------------
union H8 { uint4 u; __half2 h2[4]; };

__global__ __launch_bounds__(GTHREADS) void conv_gather_lds(
    const int*    __restrict__ words,  // [16][16384]
    const __half* __restrict__ T16,    // [3][128][304]
    const float*  __restrict__ bias,   // [300]
    float*        __restrict__ out)    // [16384][300]
{
    __shared__ __align__(16) __half sl[3 * TROWS * NCH_SL * 8];   // 61,440 B
    const int s   = blockIdx.y;                 // 0..3
    const int wg  = blockIdx.x;                 // 0..255
    const int off = (s < 3) ? s * NCH_SL : 28;  // window start chunk (max off+9 = 37)

    // ---- stage: 3*128 rows x 10 chunks = 3840 uint4, exactly 6 per thread
    {
        const uint4* __restrict__ src = (const uint4*)T16;   // row pitch 304/8 = 38
        uint4* __restrict__ dst = (uint4*)sl;                // row pitch 10
        #pragma unroll
        for (int i = threadIdx.x; i < 3 * TROWS * NCH_SL; i += GTHREADS) {
            const int row = i / NCH_SL;          // k*128 + c
            const int ch  = i - row * NCH_SL;    // 0..9 (== tid%10, invariant)
            dst[i] = src[row * (RPAD / 8) + off + ch];
        }
    }
    __syncthreads();

    // ---- compute: exactly one item per thread
    const int item = threadIdx.x;                // 0..639
    const int wloc = item / NCH_SL;
    const int ch   = item - wloc * NCH_SL;       // slice-local chunk
    const int ch8  = off + ch;                   // global chunk 0..37
    const int n    = wg * W_BLK + wloc;

    int c[MAX_WLEN];
    #pragma unroll
    for (int l = 0; l < MAX_WLEN; ++l)
        c[l] = words[l * N_WORDS + n];

    // LDS addressing: row (k*128 + letter) has pitch NCH_SL*8 = 80 halfs
    const __half* __restrict__ S = sl + ch * 8;
    #define LD(k_, c_) (*(const uint4*)(S + ((k_) * TROWS + (c_)) * (NCH_SL * 8)))

    float m[8];
    // l = 0: tap0 reads the conv zero-pad position -> taps 1,2 only
    {
        H8 b, d;
        b.u = LD(1, c[0]);
        d.u = LD(2, c[1]);
        #pragma unroll
        for (int j = 0; j < 4; ++j) {
            const float2 fb = __half22float2(b.h2[j]);
            const float2 fd = __half22float2(d.h2[j]);
            m[2 * j]     = fb.x + fd.x;
            m[2 * j + 1] = fb.y + fd.y;
        }
    }
    // l = 1..14: all 3 taps
    #pragma unroll
    for (int l = 1; l < MAX_WLEN - 1; ++l) {
        H8 a, b, d;
        a.u = LD(0, c[l - 1]);
        b.u = LD(1, c[l]);
        d.u = LD(2, c[l + 1]);
        #pragma unroll
        for (int j = 0; j < 4; ++j) {
            const float2 fa = __half22float2(a.h2[j]);
            const float2 fb = __half22float2(b.h2[j]);
            const float2 fd = __half22float2(d.h2[j]);
            m[2 * j]     = fmaxf(m[2 * j],     fa.x + fb.x + fd.x);
            m[2 * j + 1] = fmaxf(m[2 * j + 1], fa.y + fb.y + fd.y);
        }
    }
    // l = 15: tap2 reads the conv zero-pad position -> taps 0,1 only
    {
        H8 a, b;
        a.u = LD(0, c[MAX_WLEN - 2]);
        b.u = LD(1, c[MAX_WLEN - 1]);
        #pragma unroll
        for (int j = 0; j < 4; ++j) {
            const float2 fa = __half22float2(a.h2[j]);
            const float2 fb = __half22float2(b.h2[j]);
            m[2 * j]     = fmaxf(m[2 * j],     fa.x + fb.x);
            m[2 * j + 1] = fmaxf(m[2 * j + 1], fa.y + fb.y);
        }
    }
    #undef LD

    // bias + relu + store (tail chunk 37 has only 4 valid channels)
    const float4* __restrict__ bias4 = (const float4*)bias;
    float4* __restrict__ out4 = (float4*)(out + (size_t)n * HIDDEN) + ch8 * 2;

    const float4 b0 = bias4[ch8 * 2];
    float4 r0;
    r0.x = fmaxf(m[0] + b0.x, 0.0f);
    r0.y = fmaxf(m[1] + b0.y, 0.0f);
    r0.z = fmaxf(m[2] + b0.z, 0.0f);
    r0.w = fmaxf(m[3] + b0.w, 0.0f);
    out4[0] = r0;

    if (ch8 != CH8 - 1) {
        const float4 b1 = bias4[ch8 * 2 + 1];
        float4 r1;
        r1.x = fmaxf(m[4] + b1.x, 0.0f);
        r1.y = fmaxf(m[5] + b1.y, 0.0f);
        r1.z = fmaxf(m[6] + b1.z, 0.0f);
        r1.w = fmaxf(m[7] + b1.w, 0.0f);
        out4[1] = r1;
    }
}

// ---------------------------------------------------------------------------
extern "C" void kernel_launch(void* const* d_in, const int* in_sizes, int n_in,
                              void* d_out, int out_size, void* d_ws, size_t ws_size,
                              hipStream_t stream) {
    const int*   words = (const int*)  d_in[0];   // [16][16384] int32
    const float* emb   = (const float*)d_in[1];   // [128][300]
    const float* w     = (const float*)d_in[2];   // [300][300][3]
    const float* bias  = (const float*)d_in[3];   // [300]
    float*       out   = (float*)d_out;           // [16384][300]

    unsigned short* wtb = (unsigned short*)d_ws;                  // 547.2 KB bf16
    __half*         T16 = (__half*)((char*)d_ws + WTB_BYTES);     // 233.5 KB fp16

    dim3 tgrid((HIDDEN * KSIZE + 63) / 64, (HIDDEN + 63) / 64);   // 15 x 5
    transpose_w_bf16<<<tgrid, 256, 0, stream>>>(w, wtb);

    dim3 pgrid(N_LETTERS, KSIZE);                                 // 128 x 3
    precompute_f16<<<pgrid, 320, 0, stream>>>(emb, wtb, T16);

    dim3 ggrid(N_WORDS / W_BLK, 4);                               // 256 x 4
    conv_gather_lds<<<ggrid, GTHREADS, 0, stream>>>(words, T16, bias, out);
}